// Round 6
// baseline (5359.059 us; speedup 1.0000x reference)
//
#include <hip/hip_runtime.h>
#include <stdint.h>

#define DDIM 64
#define HID 128
#define TSTEPS 4000

typedef float v2f __attribute__((ext_vector_type(2)));

__device__ __forceinline__ uint32_t rotl32(uint32_t x, int r) {
  return (x << r) | (x >> (32 - r));
}

// jax threefry2x32, 20 rounds (bit-exact)
__device__ __forceinline__ void threefry(uint32_t k0, uint32_t k1, uint32_t x0,
                                         uint32_t x1, uint32_t& o0, uint32_t& o1) {
  uint32_t ks2 = 0x1BD11BDAu ^ k0 ^ k1;
  x0 += k0; x1 += k1;
#define TFR(r) { x0 += x1; x1 = rotl32(x1, r); x1 ^= x0; }
  TFR(13) TFR(15) TFR(26) TFR(6)
  x0 += k1; x1 += ks2 + 1u;
  TFR(17) TFR(29) TFR(16) TFR(24)
  x0 += ks2; x1 += k0 + 2u;
  TFR(13) TFR(15) TFR(26) TFR(6)
  x0 += k0; x1 += k1 + 3u;
  TFR(17) TFR(29) TFR(16) TFR(24)
  x0 += k1; x1 += ks2 + 4u;
  TFR(13) TFR(15) TFR(26) TFR(6)
  x0 += ks2; x1 += k0 + 5u;
#undef TFR
  o0 = x0; o1 = x1;
}

// XLA ErfInv32 (Giles), exact non-contracted op order
__device__ __forceinline__ float erfinv32(float x) {
  float w = -log1pf(__fmul_rn(-x, x));
  float ws = __fsub_rn(w, 2.5f);
  float p = 2.81022636e-08f;
  p = __fadd_rn(3.43273939e-07f,  __fmul_rn(p, ws));
  p = __fadd_rn(-3.5233877e-06f,  __fmul_rn(p, ws));
  p = __fadd_rn(-4.39150654e-06f, __fmul_rn(p, ws));
  p = __fadd_rn(0.00021858087f,   __fmul_rn(p, ws));
  p = __fadd_rn(-0.00125372503f,  __fmul_rn(p, ws));
  p = __fadd_rn(-0.00417768164f,  __fmul_rn(p, ws));
  p = __fadd_rn(0.246640727f,     __fmul_rn(p, ws));
  p = __fadd_rn(1.50140941f,      __fmul_rn(p, ws));
  float wb = __fsub_rn(__fsqrt_rn(w), 3.0f);
  float qq = -0.000200214257f;
  qq = __fadd_rn(0.000100950558f,  __fmul_rn(qq, wb));
  qq = __fadd_rn(0.00134934322f,   __fmul_rn(qq, wb));
  qq = __fadd_rn(-0.00367342844f,  __fmul_rn(qq, wb));
  qq = __fadd_rn(0.00573950773f,   __fmul_rn(qq, wb));
  qq = __fadd_rn(-0.0076224613f,   __fmul_rn(qq, wb));
  qq = __fadd_rn(0.00943887047f,   __fmul_rn(qq, wb));
  qq = __fadd_rn(1.00167406f,      __fmul_rn(qq, wb));
  qq = __fadd_rn(2.83297682f,      __fmul_rn(qq, wb));
  float r = (w < 5.0f) ? p : qq;
  return __fmul_rn(r, x);
}

// DPP quad_perm combines: xor1 = perm(1,0,3,2)=0xB1, xor2 = perm(2,3,0,1)=0x4E
__device__ __forceinline__ float dpp_xor1(float v) {
  return __int_as_float(__builtin_amdgcn_mov_dpp(__float_as_int(v), 0xB1, 0xF, 0xF, true));
}
__device__ __forceinline__ float dpp_xor2(float v) {
  return __int_as_float(__builtin_amdgcn_mov_dpp(__float_as_int(v), 0x4E, 0xF, 0xF, true));
}

__device__ __forceinline__ float beta_at(int i) {
  // jnp.linspace: start + i*delta in f32 (no endpoint forcing, unlike numpy)
  const float DELTA = (0.02f - 1e-4f) / 3999.0f;  // f32 compile-time fold = XLA fold
  return __fadd_rn(1e-4f, __fmul_rn((float)i, DELTA));
}

__global__ __launch_bounds__(256, 1) void ddpm_kernel(
    const float* __restrict__ x_init,
    const float* __restrict__ W1, const float* __restrict__ b1,
    const float* __restrict__ W2, const float* __restrict__ b2,
    const float* __restrict__ W3, const float* __restrict__ b3,
    float* __restrict__ out, int nrows) {
  const int tid = threadIdx.x;
  const int r = blockIdx.x;
  const int j = tid >> 1;   // stage1/2 output column
  const int h = tid & 1;    // stage1/2 k-half
  const int d3 = tid >> 2;  // stage3 output element
  const int q = tid & 3;    // stage3 k-quarter

  __shared__ float ab_lds[TSTEPS];
  __shared__ uint2 key_lds[TSTEPS];
  __shared__ float freqs[32];
  __shared__ float4 v4[DDIM / 4];
  __shared__ float4 h1_4[HID / 4];
  __shared__ float4 h2_4[HID / 4];
  __shared__ float pe_lds[DDIM];
  __shared__ float nz_lds[DDIM];
  __shared__ float scal[4];
  __shared__ double chunk[256];

  // ---- weights into registers (one-time) ----
  v2f w1r[16], w2r[32], w3r[16];
#pragma unroll
  for (int c = 0; c < 16; ++c) {
    int k = h * 32 + 2 * c;
    w1r[c] = (v2f){W1[k * HID + j], W1[(k + 1) * HID + j]};
  }
#pragma unroll
  for (int c = 0; c < 32; ++c) {
    int k = h * 64 + 2 * c;
    w2r[c] = (v2f){W2[k * HID + j], W2[(k + 1) * HID + j]};
  }
#pragma unroll
  for (int c = 0; c < 16; ++c) {
    int k = q * 32 + 2 * c;
    w3r[c] = (v2f){W3[k * DDIM + d3], W3[(k + 1) * DDIM + d3]};
  }
  float b1r = b1[j], b2r = b2[j], b3r = b3[d3];

  // ---- per-t tables: freqs, cumprod(double), fold-in keys ----
  if (tid < 32)
    freqs[tid] = expf(__fmul_rn(-((float)tid * 0.03125f), 9.210340371976184f));
  {
    double p = 1.0;
    int base = tid * 16;
#pragma unroll 1
    for (int m = 0; m < 16; ++m) {
      int i = base + m;
      if (i < TSTEPS) p *= (double)(__fsub_rn(1.0f, beta_at(i)));
    }
    chunk[tid] = p;
  }
  __syncthreads();
  if (tid == 0) {
    double run = 1.0;
    for (int i2 = 0; i2 < 256; ++i2) {
      double tmp = chunk[i2]; chunk[i2] = run; run *= tmp;
    }
  }
  __syncthreads();
  {
    double run = chunk[tid];
    int base = tid * 16;
#pragma unroll 1
    for (int m = 0; m < 16; ++m) {
      int i = base + m;
      if (i < TSTEPS) {
        run *= (double)(__fsub_rn(1.0f, beta_at(i)));
        ab_lds[i] = (float)run;
      }
    }
  }
#pragma unroll 1
  for (int t = tid; t < TSTEPS; t += 256) {
    uint32_t y0, y1;
    threefry(0u, 42u, 0u, (uint32_t)t, y0, y1);
    key_lds[t] = make_uint2(y0, y1);
  }
  __syncthreads();

  // ---- init x and v = x + pe(3999) ----
  float* vf = (float*)v4;
  float* h1f = (float*)h1_4;
  float* h2f = (float*)h2_4;

  float xr = 0.0f;
  if (q == 0) xr = x_init[r * DDIM + d3];
  if (q == 1) {  // pe(t): waves 0-1 sin, waves 2-3 cos (wave-uniform branch)
    float tf = 3999.0f;
    if (d3 < 32) pe_lds[2 * d3] = sinf(__fmul_rn(freqs[d3], tf));
    else pe_lds[2 * (d3 - 32) + 1] = cosf(__fmul_rn(freqs[d3 - 32], tf));
  }
  __syncthreads();
  if (q == 0) vf[d3] = __fadd_rn(xr, pe_lds[d3]);
  __syncthreads();

  const float SQRT2 = 1.4142135623730951f;
  const float LO = -0.99999994f;

#pragma unroll 1
  for (int t = 3999; t >= 1; --t) {
    // ======== phase A: stage1 (h1 = relu(v@W1+b1)); wave0: noise; lane64: scalars
    v2f acc = (v2f){0.f, 0.f};
#pragma unroll
    for (int c = 0; c < 8; ++c) {
      float4 vv = v4[h * 8 + c];
      acc += w1r[2 * c] * (v2f){vv.x, vv.y};
      acc += w1r[2 * c + 1] * (v2f){vv.z, vv.w};
    }
    float s = acc.x + acc.y;
    s += dpp_xor1(s);
    float h1v = fmaxf(__fadd_rn(s, b1r), 0.0f);
    if (h == 0) h1f[j] = h1v;

    if (tid < DDIM) {  // wave 0: raw_noise for this t (partitionable threefry)
      uint2 kk = key_lds[t];
      uint32_t e = (uint32_t)(r * DDIM + tid);  // flat element index; count64 = e -> (hi,lo)=(0,e)
      uint32_t y0, y1;
      threefry(kk.x, kk.y, 0u, e, y0, y1);
      uint32_t bits = y0 ^ y1;                  // 32-bit draws = bits1 ^ bits2
      float f = __uint_as_float((bits >> 9) | 0x3f800000u);
      float u = __fadd_rn(__fmul_rn(__fsub_rn(f, 1.0f), 2.0f), LO);
      u = fmaxf(u, LO);
      nz_lds[tid] = __fmul_rn(SQRT2, erfinv32(u));
    } else if (tid == 64) {  // per-step scalars c1,c2,c3
      float beta = beta_at(t);
      float a = __fsub_rn(1.0f, beta);
      float ab = ab_lds[t];
      scal[0] = __fdiv_rn(1.0f, __fsqrt_rn(a));
      scal[1] = __fdiv_rn(beta, __fsqrt_rn(__fsub_rn(1.0f, ab)));
      scal[2] = __fsqrt_rn(beta);
    }
    __syncthreads();

    // ======== phase B: stage2 (h2 = relu(h1@W2+b2)); q==1 lanes: pe(t-1)
    acc = (v2f){0.f, 0.f};
#pragma unroll
    for (int c = 0; c < 16; ++c) {
      float4 hv = h1_4[h * 16 + c];
      acc += w2r[2 * c] * (v2f){hv.x, hv.y};
      acc += w2r[2 * c + 1] * (v2f){hv.z, hv.w};
    }
    s = acc.x + acc.y;
    s += dpp_xor1(s);
    float h2v = fmaxf(__fadd_rn(s, b2r), 0.0f);
    if (h == 0) h2f[j] = h2v;

    if (q == 1) {
      float tf = (float)(t - 1);
      if (d3 < 32) pe_lds[2 * d3] = sinf(__fmul_rn(freqs[d3], tf));
      else pe_lds[2 * (d3 - 32) + 1] = cosf(__fmul_rn(freqs[d3 - 32], tf));
    }
    __syncthreads();

    // ======== phase C: stage3 (o = h2@W3+b3) + x update + v for next step
    acc = (v2f){0.f, 0.f};
#pragma unroll
    for (int c = 0; c < 8; ++c) {
      int cc = (c + 2 * q) & 7;  // rotate reads: 4 distinct bank groups per quad
      float4 hv = h2_4[q * 8 + cc];
      acc += w3r[2 * cc] * (v2f){hv.x, hv.y};
      acc += w3r[2 * cc + 1] * (v2f){hv.z, hv.w};
    }
    s = acc.x + acc.y;
    s += dpp_xor1(s);
    s += dpp_xor2(s);
    if (q == 0) {
      float o = __fadd_rn(s, b3r);
      float c1 = scal[0], c2 = scal[1], c3 = scal[2];
      float xn = __fadd_rn(__fmul_rn(c1, __fsub_rn(xr, __fmul_rn(c2, o))),
                           __fmul_rn(c3, nz_lds[d3]));
      xr = xn;
      vf[d3] = __fadd_rn(xn, pe_lds[d3]);
    }
    __syncthreads();
  }

  if (q == 0) out[r * DDIM + d3] = xr;
}

extern "C" void kernel_launch(void* const* d_in, const int* in_sizes, int n_in,
                              void* d_out, int out_size, void* d_ws, size_t ws_size,
                              hipStream_t stream) {
  const float* x_init = (const float*)d_in[1];
  const float* W1 = (const float*)d_in[2];
  const float* b1 = (const float*)d_in[3];
  const float* W2 = (const float*)d_in[4];
  const float* b2 = (const float*)d_in[5];
  const float* W3 = (const float*)d_in[6];
  const float* b3 = (const float*)d_in[7];
  int nrows = in_sizes[1] / DDIM;  // 256
  ddpm_kernel<<<nrows, 256, 0, stream>>>(x_init, W1, b1, W2, b2, W3, b3,
                                         (float*)d_out, nrows);
}

// Round 20
// 3880.973 us; speedup vs baseline: 1.3809x; 1.3809x over previous
//
#include <hip/hip_runtime.h>
#include <stdint.h>

#define DDIM 64
#define HID 128
#define TSTEPS 4000
#define SB 16

typedef float v2f __attribute__((ext_vector_type(2)));

__device__ __forceinline__ uint32_t rotl32(uint32_t x, int r) {
  return (x << r) | (x >> (32 - r));
}

// jax threefry2x32, 20 rounds (bit-exact)
__device__ __forceinline__ void threefry(uint32_t k0, uint32_t k1, uint32_t x0,
                                         uint32_t x1, uint32_t& o0, uint32_t& o1) {
  uint32_t ks2 = 0x1BD11BDAu ^ k0 ^ k1;
  x0 += k0; x1 += k1;
#define TFR(r) { x0 += x1; x1 = rotl32(x1, r); x1 ^= x0; }
  TFR(13) TFR(15) TFR(26) TFR(6)
  x0 += k1; x1 += ks2 + 1u;
  TFR(17) TFR(29) TFR(16) TFR(24)
  x0 += ks2; x1 += k0 + 2u;
  TFR(13) TFR(15) TFR(26) TFR(6)
  x0 += k0; x1 += k1 + 3u;
  TFR(17) TFR(29) TFR(16) TFR(24)
  x0 += k1; x1 += ks2 + 4u;
  TFR(13) TFR(15) TFR(26) TFR(6)
  x0 += ks2; x1 += k0 + 5u;
#undef TFR
  o0 = x0; o1 = x1;
}

// Giles erfinv (same values as r6 pass)
__device__ __forceinline__ float erfinv32(float x) {
  float w = -log1pf(__fmul_rn(-x, x));
  float ws = __fsub_rn(w, 2.5f);
  float p = 2.81022636e-08f;
  p = __fadd_rn(3.43273939e-07f,  __fmul_rn(p, ws));
  p = __fadd_rn(-3.5233877e-06f,  __fmul_rn(p, ws));
  p = __fadd_rn(-4.39150654e-06f, __fmul_rn(p, ws));
  p = __fadd_rn(0.00021858087f,   __fmul_rn(p, ws));
  p = __fadd_rn(-0.00125372503f,  __fmul_rn(p, ws));
  p = __fadd_rn(-0.00417768164f,  __fmul_rn(p, ws));
  p = __fadd_rn(0.246640727f,     __fmul_rn(p, ws));
  p = __fadd_rn(1.50140941f,      __fmul_rn(p, ws));
  float wb = __fsub_rn(__fsqrt_rn(w), 3.0f);
  float qq = -0.000200214257f;
  qq = __fadd_rn(0.000100950558f,  __fmul_rn(qq, wb));
  qq = __fadd_rn(0.00134934322f,   __fmul_rn(qq, wb));
  qq = __fadd_rn(-0.00367342844f,  __fmul_rn(qq, wb));
  qq = __fadd_rn(0.00573950773f,   __fmul_rn(qq, wb));
  qq = __fadd_rn(-0.0076224613f,   __fmul_rn(qq, wb));
  qq = __fadd_rn(0.00943887047f,   __fmul_rn(qq, wb));
  qq = __fadd_rn(1.00167406f,      __fmul_rn(qq, wb));
  qq = __fadd_rn(2.83297682f,      __fmul_rn(qq, wb));
  float rr = (w < 5.0f) ? p : qq;
  return __fmul_rn(rr, x);
}

__device__ __forceinline__ float dpp_xor1(float v) {
  return __int_as_float(__builtin_amdgcn_mov_dpp(__float_as_int(v), 0xB1, 0xF, 0xF, true));
}
__device__ __forceinline__ float dpp_xor2(float v) {
  return __int_as_float(__builtin_amdgcn_mov_dpp(__float_as_int(v), 0x4E, 0xF, 0xF, true));
}
// 8-lane reduction: xor1 + xor2 (DPP quad_perm) + xor4 (ds_swizzle 0x101F)
__device__ __forceinline__ float red8(float x) {
  x += dpp_xor1(x);
  x += dpp_xor2(x);
  x += __int_as_float(__builtin_amdgcn_ds_swizzle(__float_as_int(x), 0x101F));
  return x;
}

__device__ __forceinline__ float beta_at(int i) {
  const float DELTA = (0.02f - 1e-4f) / 3999.0f;
  return __fadd_rn(1e-4f, __fmul_rn((float)i, DELTA));
}

__global__ __launch_bounds__(256, 1) void ddpm_kernel(
    const float* __restrict__ x_init,
    const float* __restrict__ W1, const float* __restrict__ b1,
    const float* __restrict__ W2, const float* __restrict__ b2,
    const float* __restrict__ W3, const float* __restrict__ b3,
    float* __restrict__ out, int nrows) {
  const int tid = threadIdx.x;
  const int r = blockIdx.x;
  const int k8 = tid & 7;    // k-eighth
  const int g  = tid >> 3;   // 0..31: stage1/2 output block 4g..4g+3; stage3 outputs 2g,2g+1

  __shared__ float  ab_lds[TSTEPS];
  __shared__ uint2  key_lds[TSTEPS];
  __shared__ float  freqs[32];
  __shared__ float4 vbuf4[DDIM / 4];       // v = x + pe, 64 floats
  __shared__ float4 h1s[40];               // 128 floats + 4-per-16 padding
  __shared__ float4 h2s[40];
  __shared__ float2 nz2s[SB][DDIM / 2];    // burst noise
  __shared__ float2 pe2s[SB][DDIM / 2];    // burst pe(t-1)
  __shared__ float4 scal16[SB];            // c1,c2,c3 per step
  __shared__ float2 pe0v[DDIM / 2];        // pe(3999)
  __shared__ double chunk[256];

  // ---- weights into registers ----
  v2f w1a[8], w1b[8];
#pragma unroll
  for (int kk = 0; kk < 8; ++kk) {
    int k = k8 * 8 + kk;
    float4 w = *(const float4*)&W1[k * HID + 4 * g];
    w1a[kk] = (v2f){w.x, w.y};
    w1b[kk] = (v2f){w.z, w.w};
  }
  v2f w2a[16], w2b[16];
#pragma unroll
  for (int kk = 0; kk < 16; ++kk) {
    int k = k8 * 16 + kk;
    float4 w = *(const float4*)&W2[k * HID + 4 * g];
    w2a[kk] = (v2f){w.x, w.y};
    w2b[kk] = (v2f){w.z, w.w};
  }
  v2f w3r[16];
#pragma unroll
  for (int kk = 0; kk < 16; ++kk) {
    int k = k8 * 16 + kk;
    float2 w = *(const float2*)&W3[k * DDIM + 2 * g];
    w3r[kk] = (v2f){w.x, w.y};
  }
  float4 b1r = *(const float4*)&b1[4 * g];
  float4 b2r = *(const float4*)&b2[4 * g];
  float2 b3r = *(const float2*)&b3[2 * g];

  // ---- one-time tables ----
  const float LN1E4 = 9.210340371976184f;
  if (tid < 32) {
    float fr = expf(__fmul_rn(-((float)tid * 0.03125f), LN1E4));
    freqs[tid] = fr;
    ((float*)pe0v)[2 * tid] = sinf(__fmul_rn(fr, 3999.0f));
  } else if (tid < 64) {
    float fr = expf(__fmul_rn(-((float)(tid - 32) * 0.03125f), LN1E4));
    ((float*)pe0v)[2 * (tid - 32) + 1] = cosf(__fmul_rn(fr, 3999.0f));
  }
#pragma unroll 1
  for (int t = tid; t < TSTEPS; t += 256) {
    uint32_t y0, y1;
    threefry(0u, 42u, 0u, (uint32_t)t, y0, y1);
    key_lds[t] = make_uint2(y0, y1);
  }
  {
    double p = 1.0;
    int base = tid * 16;
#pragma unroll 1
    for (int m = 0; m < 16; ++m) {
      int i = base + m;
      if (i < TSTEPS) p *= (double)(__fsub_rn(1.0f, beta_at(i)));
    }
    chunk[tid] = p;
  }
  __syncthreads();
  if (tid == 0) {
    double run = 1.0;
    for (int i2 = 0; i2 < 256; ++i2) {
      double tmp = chunk[i2]; chunk[i2] = run; run *= tmp;
    }
  }
  __syncthreads();
  {
    double run = chunk[tid];
    int base = tid * 16;
#pragma unroll 1
    for (int m = 0; m < 16; ++m) {
      int i = base + m;
      if (i < TSTEPS) {
        run *= (double)(__fsub_rn(1.0f, beta_at(i)));
        ab_lds[i] = (float)run;
      }
    }
  }

  // ---- x state + initial v ----
  float2 x2 = {0.f, 0.f};
  if (k8 == 0) x2 = *(const float2*)&x_init[r * DDIM + 2 * g];
  __syncthreads();  // ab_lds + pe0v ready
  if (k8 == 0) {
    float2 p = pe0v[g];
    float2 vn = {x2.x + p.x, x2.y + p.y};
    ((float2*)vbuf4)[g] = vn;
  }
  __syncthreads();

  const float SQRT2C = 1.4142135623730951f;
  const float LO = -0.99999994f;

#pragma unroll 1
  for (int tb = 3999; tb >= 1; tb -= SB) {
    const int ns = (tb < SB) ? tb : SB;
    // ======== burst: noise bits (exact stream), pe, scalars ========
#pragma unroll
    for (int m = 0; m < 4; ++m) {
      int i = tid + 256 * m;
      int s = i >> 6, d = i & 63;
      if (s < ns) {
        int t = tb - s;
        uint2 kk = key_lds[t];
        uint32_t y0, y1;
        threefry(kk.x, kk.y, 0u, (uint32_t)(r * DDIM + d), y0, y1);
        uint32_t bits = y0 ^ y1;
        float f = __uint_as_float((bits >> 9) | 0x3f800000u);
        float u = __fadd_rn(__fmul_rn(__fsub_rn(f, 1.0f), 2.0f), LO);
        u = fmaxf(u, LO);
        ((float*)nz2s)[s * DDIM + d] = __fmul_rn(SQRT2C, erfinv32(u));
      }
    }
    {
      int base = tid & 127;
      if (tid < 128) {
#pragma unroll
        for (int m = 0; m < 4; ++m) {
          int i = base + 128 * m;
          int s = i >> 5, k = i & 31;
          if (s < ns)
            ((float*)pe2s)[s * DDIM + 2 * k] =
                sinf(__fmul_rn(freqs[k], (float)(tb - s - 1)));
        }
      } else {
#pragma unroll
        for (int m = 0; m < 4; ++m) {
          int i = base + 128 * m;
          int s = i >> 5, k = i & 31;
          if (s < ns)
            ((float*)pe2s)[s * DDIM + 2 * k + 1] =
                cosf(__fmul_rn(freqs[k], (float)(tb - s - 1)));
        }
      }
    }
    if (tid < ns) {
      int t = tb - tid;
      float beta = beta_at(t);
      float a = __fsub_rn(1.0f, beta);
      float ab = ab_lds[t];
      float4 sc;
      sc.x = __fdiv_rn(1.0f, __fsqrt_rn(a));
      sc.y = __fdiv_rn(beta, __fsqrt_rn(__fsub_rn(1.0f, ab)));
      sc.z = __fsqrt_rn(beta);
      sc.w = 0.f;
      scal16[tid] = sc;
    }
    __syncthreads();

    // ======== 16 steps of pure 3-phase MLP ========
#pragma unroll 1
    for (int s = 0; s < ns; ++s) {
      // --- phase A: h1 = relu(v @ W1 + b1), splitK=8 ---
      {
        float4 va = vbuf4[2 * k8];
        float4 vb = vbuf4[2 * k8 + 1];
        v2f a01 = {0.f, 0.f}, a23 = {0.f, 0.f};
#define FMA1(VK, IX) { v2f vv = {VK, VK}; a01 += vv * w1a[IX]; a23 += vv * w1b[IX]; }
        FMA1(va.x, 0) FMA1(va.y, 1) FMA1(va.z, 2) FMA1(va.w, 3)
        FMA1(vb.x, 4) FMA1(vb.y, 5) FMA1(vb.z, 6) FMA1(vb.w, 7)
#undef FMA1
        float r0 = red8(a01.x), r1 = red8(a01.y);
        float r2 = red8(a23.x), r3 = red8(a23.y);
        if (k8 == 0) {
          float4 hh;
          hh.x = fmaxf(r0 + b1r.x, 0.f);
          hh.y = fmaxf(r1 + b1r.y, 0.f);
          hh.z = fmaxf(r2 + b1r.z, 0.f);
          hh.w = fmaxf(r3 + b1r.w, 0.f);
          h1s[g + (g >> 2)] = hh;  // padded: chunk stride 20 floats
        }
      }
      __syncthreads();
      // --- phase B: h2 = relu(h1 @ W2 + b2), splitK=8 ---
      {
        const float* h1f = (const float*)h1s;
        int fp = k8 * 20;
        float4 ha = *(const float4*)(h1f + fp);
        float4 hb = *(const float4*)(h1f + fp + 4);
        float4 hc = *(const float4*)(h1f + fp + 8);
        float4 hd = *(const float4*)(h1f + fp + 12);
        v2f a01 = {0.f, 0.f}, a23 = {0.f, 0.f};
#define FMA2(VK, IX) { v2f vv = {VK, VK}; a01 += vv * w2a[IX]; a23 += vv * w2b[IX]; }
        FMA2(ha.x, 0)  FMA2(ha.y, 1)  FMA2(ha.z, 2)  FMA2(ha.w, 3)
        FMA2(hb.x, 4)  FMA2(hb.y, 5)  FMA2(hb.z, 6)  FMA2(hb.w, 7)
        FMA2(hc.x, 8)  FMA2(hc.y, 9)  FMA2(hc.z, 10) FMA2(hc.w, 11)
        FMA2(hd.x, 12) FMA2(hd.y, 13) FMA2(hd.z, 14) FMA2(hd.w, 15)
#undef FMA2
        float r0 = red8(a01.x), r1 = red8(a01.y);
        float r2 = red8(a23.x), r3 = red8(a23.y);
        if (k8 == 0) {
          float4 hh;
          hh.x = fmaxf(r0 + b2r.x, 0.f);
          hh.y = fmaxf(r1 + b2r.y, 0.f);
          hh.z = fmaxf(r2 + b2r.z, 0.f);
          hh.w = fmaxf(r3 + b2r.w, 0.f);
          h2s[g + (g >> 2)] = hh;
        }
      }
      __syncthreads();
      // --- phase C: o = h2 @ W3 + b3; x update; v for next step ---
      {
        const float* h2f = (const float*)h2s;
        int fp = k8 * 20;
        float4 pa = *(const float4*)(h2f + fp);
        float4 pb = *(const float4*)(h2f + fp + 4);
        float4 pc = *(const float4*)(h2f + fp + 8);
        float4 pd = *(const float4*)(h2f + fp + 12);
        v2f a = {0.f, 0.f};
#define FMA3(VK, IX) { v2f vv = {VK, VK}; a += vv * w3r[IX]; }
        FMA3(pa.x, 0)  FMA3(pa.y, 1)  FMA3(pa.z, 2)  FMA3(pa.w, 3)
        FMA3(pb.x, 4)  FMA3(pb.y, 5)  FMA3(pb.z, 6)  FMA3(pb.w, 7)
        FMA3(pc.x, 8)  FMA3(pc.y, 9)  FMA3(pc.z, 10) FMA3(pc.w, 11)
        FMA3(pd.x, 12) FMA3(pd.y, 13) FMA3(pd.z, 14) FMA3(pd.w, 15)
#undef FMA3
        float o0 = red8(a.x), o1 = red8(a.y);
        if (k8 == 0) {
          float4 sc = scal16[s];
          float ox = o0 + b3r.x, oy = o1 + b3r.y;
          float2 nz = nz2s[s][g];
          float2 pe = pe2s[s][g];
          x2.x = sc.x * (x2.x - sc.y * ox) + sc.z * nz.x;
          x2.y = sc.x * (x2.y - sc.y * oy) + sc.z * nz.y;
          float2 vn = {x2.x + pe.x, x2.y + pe.y};
          ((float2*)vbuf4)[g] = vn;
        }
      }
      __syncthreads();
    }
  }

  if (k8 == 0) *(float2*)&out[r * DDIM + 2 * g] = x2;
}

extern "C" void kernel_launch(void* const* d_in, const int* in_sizes, int n_in,
                              void* d_out, int out_size, void* d_ws, size_t ws_size,
                              hipStream_t stream) {
  (void)d_ws; (void)ws_size; (void)n_in; (void)out_size;
  const float* x_init = (const float*)d_in[1];
  const float* W1 = (const float*)d_in[2];
  const float* b1 = (const float*)d_in[3];
  const float* W2 = (const float*)d_in[4];
  const float* b2 = (const float*)d_in[5];
  const float* W3 = (const float*)d_in[6];
  const float* b3 = (const float*)d_in[7];
  int nrows = in_sizes[1] / DDIM;  // 256
  ddpm_kernel<<<nrows, 256, 0, stream>>>(x_init, W1, b1, W2, b2, W3, b3,
                                         (float*)d_out, nrows);
}